// Round 8
// baseline (501.125 us; speedup 1.0000x reference)
//
#include <hip/hip_runtime.h>

#define EMB 64
#define CH 4096
#define ST 65

// ---------------------------------------------------------------------------
// Round 8: fix the fused agg64 regression (107us vs 79us standalone).
//  Counters showed SQ_LDS_BANK_CONFLICT=3.2M (xt[f][r] stride-68 stores ->
//  8-way conflicts) and an 8-deep sequential per-wave node loop.
//  - xt layout transposed to [r][f] stride 65: stores 2 lanes/bank (free),
//    GEMM reads scalar xt[r*65+k] (4 addrs broadcast x16 -> free).
//  - 1024-thread blocks (16 waves), 4 sequential nodes/wave (was 8).
//    LDS 33KB -> 2 blocks/CU (thread-limited) = 32 waves/CU, max occupancy.
// Rest identical to round 7.
// ---------------------------------------------------------------------------

static __device__ __forceinline__ unsigned short f2bf(float x) {
    union { float f; unsigned u; } v; v.f = x;
    unsigned r = v.u + 0x7fffu + ((v.u >> 16) & 1u);   // RNE
    return (unsigned short)(r >> 16);
}
static __device__ __forceinline__ float bflo(unsigned w) {
    union { unsigned u; float f; } v; v.u = w << 16; return v.f;
}
static __device__ __forceinline__ float bfhi(unsigned w) {
    union { unsigned u; float f; } v; v.u = w & 0xffff0000u; return v.f;
}

__global__ __launch_bounds__(256) void zero_int_kernel(int* __restrict__ p, int n) {
    int i = blockIdx.x * 256 + threadIdx.x;
    if (i < n) p[i] = 0;
}

__global__ __launch_bounds__(256) void bucket_hist_kernel(
    const int* __restrict__ src, const int* __restrict__ dst, int E,
    int* __restrict__ bkt_cnt_c, int* __restrict__ bkt_cnt_v,
    int shc, int shv, int NBC, int NBV)
{
    __shared__ int hc[512], hv[512];
    int t = threadIdx.x;
    int base = blockIdx.x * CH;
    int n = min(CH, E - base);
    for (int i = t; i < NBC; i += 256) hc[i] = 0;
    for (int i = t; i < NBV; i += 256) hv[i] = 0;
    __syncthreads();
    for (int li = t; li < n; li += 256) {
        atomicAdd(&hc[src[base + li] >> shc], 1);
        atomicAdd(&hv[dst[base + li] >> shv], 1);
    }
    __syncthreads();
    for (int i = t; i < NBC; i += 256) { int c = hc[i]; if (c) atomicAdd(&bkt_cnt_c[i], c); }
    for (int i = t; i < NBV; i += 256) { int c = hv[i]; if (c) atomicAdd(&bkt_cnt_v[i], c); }
}

// one block: exclusive-scan both bucket-count arrays in place; data[n] = E
__global__ __launch_bounds__(256) void scan_buckets_kernel(
    int* __restrict__ bc, int nbc, int* __restrict__ bv, int nbv, int E)
{
    __shared__ int sc[256];
    int t = threadIdx.x;
    {
        int v0 = (2 * t < nbc) ? bc[2 * t] : 0;
        int v1 = (2 * t + 1 < nbc) ? bc[2 * t + 1] : 0;
        sc[t] = v0 + v1;
        __syncthreads();
        for (int off = 1; off < 256; off <<= 1) {
            int x = (t >= off) ? sc[t - off] : 0;
            __syncthreads();
            sc[t] += x;
            __syncthreads();
        }
        int ex = (t > 0) ? sc[t - 1] : 0;
        if (2 * t < nbc) bc[2 * t] = ex;
        if (2 * t + 1 < nbc) bc[2 * t + 1] = ex + v0;
        if (t == 0) bc[nbc] = E;
        __syncthreads();
    }
    {
        int v0 = (2 * t < nbv) ? bv[2 * t] : 0;
        int v1 = (2 * t + 1 < nbv) ? bv[2 * t + 1] : 0;
        sc[t] = v0 + v1;
        __syncthreads();
        for (int off = 1; off < 256; off <<= 1) {
            int x = (t >= off) ? sc[t - off] : 0;
            __syncthreads();
            sc[t] += x;
            __syncthreads();
        }
        int ex = (t > 0) ? sc[t - 1] : 0;
        if (2 * t < nbv) bv[2 * t] = ex;
        if (2 * t + 1 < nbv) bv[2 * t + 1] = ex + v0;
        if (t == 0) bv[nbv] = E;
    }
}

// Phase 1: per-chunk LDS binning; packed u32 {local_node<<23 | other}.
__global__ __launch_bounds__(256) void bin_edges_kernel(
    const int* __restrict__ src, const int* __restrict__ dst, int E,
    const int* __restrict__ bb_c, const int* __restrict__ bb_v,
    int* __restrict__ gcur_c, int* __restrict__ gcur_v,
    unsigned* __restrict__ tmp_c, unsigned* __restrict__ tmp_v,
    int shc, int shv, int NBC, int NBV)
{
    __shared__ int hc[512], hv[512];
    int t = threadIdx.x;
    int base = blockIdx.x * CH;
    int n = min(CH, E - base);
    unsigned mc = (1u << shc) - 1u, mv = (1u << shv) - 1u;

    for (int i = t; i < NBC; i += 256) hc[i] = 0;
    for (int i = t; i < NBV; i += 256) hv[i] = 0;
    __syncthreads();

    int ss[16], dd[16];
#pragma unroll
    for (int q = 0; q < 16; ++q) {
        int li = t + q * 256;
        bool ok = li < n;
        ss[q] = ok ? src[base + li] : -1;
        dd[q] = ok ? dst[base + li] : -1;
        if (ok) {
            atomicAdd(&hc[ss[q] >> shc], 1);
            atomicAdd(&hv[dd[q] >> shv], 1);
        }
    }
    __syncthreads();

    for (int i = t; i < NBC; i += 256) {
        int c = hc[i];
        hc[i] = c ? (bb_c[i] + atomicAdd(&gcur_c[i], c)) : 0;
    }
    for (int i = t; i < NBV; i += 256) {
        int c = hv[i];
        hv[i] = c ? (bb_v[i] + atomicAdd(&gcur_v[i], c)) : 0;
    }
    __syncthreads();

#pragma unroll
    for (int q = 0; q < 16; ++q) {
        int li = t + q * 256;
        if (li < n) {
            unsigned s = (unsigned)ss[q], d = (unsigned)dd[q];
            int pc = atomicAdd(&hc[s >> shc], 1);
            tmp_c[pc] = ((s & mc) << 23) | d;
            int pv = atomicAdd(&hv[d >> shv], 1);
            tmp_v[pv] = ((d & mv) << 23) | s;
        }
    }
}

// Phase 2: wg-per-bucket. LDS per-node hist -> scan -> rp; rank -> adj.
__global__ __launch_bounds__(256) void regroup2_kernel(
    const unsigned* __restrict__ tmp, const int* __restrict__ bb,
    int* __restrict__ rp, int* __restrict__ adj, int n_nodes, int sh, int E, int nb)
{
    __shared__ int cnt[512];
    __shared__ int offs[512];
    __shared__ int sc[256];
    int t = threadIdx.x;
    int b = blockIdx.x;
    int node0 = b << sh;
    int node1 = min(node0 + (1 << sh), n_nodes);
    int nn = node1 - node0;
    for (int i = t; i < nn; i += 256) cnt[i] = 0;
    __syncthreads();
    int beg = bb[b], end = bb[b + 1];
    for (int e = beg + t; e < end; e += 256)
        atomicAdd(&cnt[tmp[e] >> 23], 1);
    __syncthreads();
    int v0 = (2 * t < nn) ? cnt[2 * t] : 0;
    int v1 = (2 * t + 1 < nn) ? cnt[2 * t + 1] : 0;
    sc[t] = v0 + v1;
    __syncthreads();
    for (int off = 1; off < 256; off <<= 1) {
        int x = (t >= off) ? sc[t - off] : 0;
        __syncthreads();
        sc[t] += x;
        __syncthreads();
    }
    int ex = (t > 0) ? sc[t - 1] : 0;
    if (2 * t < nn) offs[2 * t] = ex;
    if (2 * t + 1 < nn) offs[2 * t + 1] = ex + v0;
    __syncthreads();
    for (int i = t; i < nn; i += 256) {
        rp[node0 + i] = beg + offs[i];
        cnt[i] = 0;
    }
    if (b == nb - 1 && t == 0) rp[n_nodes] = E;
    __syncthreads();
    for (int e = beg + t; e < end; e += 256) {
        unsigned p = tmp[e];
        int d = (int)(p >> 23);
        int r = atomicAdd(&cnt[d], 1);
        adj[beg + offs[d] + r] = (int)(p & 0x7fffffu);
    }
}

// Fully fused node pipeline:
//   xhat = relu(relu(((x+shift)*scale)@W1+b1)@W2+b2)   (LDS only)
//   tb   = bf16(xhat @ Wll)      (layer-0 gather table)
//   u    = xhat @ Wlr            (layer-0 self term, f32)
template <int NF>
__global__ __launch_bounds__(256) void embed_fused_kernel(
    const float* __restrict__ x, const float* __restrict__ shift, const float* __restrict__ scale,
    const float* __restrict__ w1, const float* __restrict__ b1,
    const float* __restrict__ w2, const float* __restrict__ b2,
    const float* __restrict__ wll, const float* __restrict__ wlr,
    unsigned short* __restrict__ tb, float* __restrict__ u, int n)
{
    __shared__ float xs[NF * 68];
    __shared__ float w1s[NF * EMB];
    __shared__ float hs[EMB * 68];    // h, then xhat (transposed [k][r])
    __shared__ float ws[EMB * EMB];   // w2 -> wll -> wlr
    __shared__ float b1s[EMB], b2s[EMB];

    int t = threadIdx.x;
    long row0 = (long)blockIdx.x * 64;
    int nrow = (int)((n - row0 < 64) ? (n - row0) : 64);

    for (int i = t; i < NF * EMB; i += 256) w1s[i] = w1[i];
    if (t < EMB) { b1s[t] = b1[t]; b2s[t] = b2[t]; }
    {
        const float4* wg = (const float4*)w2;
        float4* wl = (float4*)ws;
#pragma unroll
        for (int q = 0; q < 4; ++q) wl[t + q * 256] = wg[t + q * 256];
    }
    for (int i = t; i < 64 * NF; i += 256) {
        int r = i / NF, k = i - r * NF;
        float v = (r < nrow) ? x[row0 * NF + i] : 0.f;
        xs[k * 68 + r] = (v + shift[k]) * scale[k];
    }
    __syncthreads();

    int r0 = (t >> 4) * 4;
    int c0 = (t & 15) * 4;

    // GEMM1: h = relu(xs @ W1 + b1), stored transposed into hs
    {
        float a1[4][4] = {{0.f}};
#pragma unroll
        for (int k = 0; k < NF; ++k) {
            float4 xv = *(const float4*)&xs[k * 68 + r0];
            float4 wv = *(const float4*)&w1s[k * EMB + c0];
            float xa[4] = {xv.x, xv.y, xv.z, xv.w};
            float wa[4] = {wv.x, wv.y, wv.z, wv.w};
#pragma unroll
            for (int i = 0; i < 4; ++i)
#pragma unroll
                for (int j = 0; j < 4; ++j)
                    a1[i][j] = fmaf(xa[i], wa[j], a1[i][j]);
        }
#pragma unroll
        for (int j = 0; j < 4; ++j) {
            float b = b1s[c0 + j];
            float4 o;
            o.x = fmaxf(a1[0][j] + b, 0.f);
            o.y = fmaxf(a1[1][j] + b, 0.f);
            o.z = fmaxf(a1[2][j] + b, 0.f);
            o.w = fmaxf(a1[3][j] + b, 0.f);
            *(float4*)&hs[(c0 + j) * 68 + r0] = o;
        }
    }
    __syncthreads();

    // GEMM2: xhat = relu(h @ W2 + b2) -> regs
    float a2[4][4] = {{0.f}};
#pragma unroll 8
    for (int k = 0; k < EMB; ++k) {
        float4 xv = *(const float4*)&hs[k * 68 + r0];
        float4 wv = *(const float4*)&ws[k * EMB + c0];
        float xa[4] = {xv.x, xv.y, xv.z, xv.w};
        float wa[4] = {wv.x, wv.y, wv.z, wv.w};
#pragma unroll
        for (int i = 0; i < 4; ++i)
#pragma unroll
            for (int j = 0; j < 4; ++j)
                a2[i][j] = fmaf(xa[i], wa[j], a2[i][j]);
    }
    __syncthreads();   // all reads of hs (h) and ws (w2) complete

    // store xhat into hs (transposed) ; stage wll into ws
#pragma unroll
    for (int j = 0; j < 4; ++j) {
        float b = b2s[c0 + j];
        float4 o;
        o.x = fmaxf(a2[0][j] + b, 0.f);
        o.y = fmaxf(a2[1][j] + b, 0.f);
        o.z = fmaxf(a2[2][j] + b, 0.f);
        o.w = fmaxf(a2[3][j] + b, 0.f);
        *(float4*)&hs[(c0 + j) * 68 + r0] = o;
    }
    {
        const float4* wg = (const float4*)wll;
        float4* wl = (float4*)ws;
#pragma unroll
        for (int q = 0; q < 4; ++q) wl[t + q * 256] = wg[t + q * 256];
    }
    __syncthreads();

    // GEMM3: t = xhat @ Wll -> bf16 table
    {
        float a3[4][4] = {{0.f}};
#pragma unroll 8
        for (int k = 0; k < EMB; ++k) {
            float4 xv = *(const float4*)&hs[k * 68 + r0];
            float4 wv = *(const float4*)&ws[k * EMB + c0];
            float xa[4] = {xv.x, xv.y, xv.z, xv.w};
            float wa[4] = {wv.x, wv.y, wv.z, wv.w};
#pragma unroll
            for (int i = 0; i < 4; ++i)
#pragma unroll
                for (int j = 0; j < 4; ++j)
                    a3[i][j] = fmaf(xa[i], wa[j], a3[i][j]);
        }
#pragma unroll
        for (int i = 0; i < 4; ++i) {
            long gr = row0 + r0 + i;
            if (gr < n) {
                ushort4 o;
                o.x = f2bf(a3[i][0]); o.y = f2bf(a3[i][1]);
                o.z = f2bf(a3[i][2]); o.w = f2bf(a3[i][3]);
                *(ushort4*)(tb + gr * EMB + c0) = o;
            }
        }
    }
    __syncthreads();   // all reads of ws (wll) complete

    {
        const float4* wg = (const float4*)wlr;
        float4* wl = (float4*)ws;
#pragma unroll
        for (int q = 0; q < 4; ++q) wl[t + q * 256] = wg[t + q * 256];
    }
    __syncthreads();

    // GEMM4: u = xhat @ Wlr -> f32
    {
        float a4[4][4] = {{0.f}};
#pragma unroll 8
        for (int k = 0; k < EMB; ++k) {
            float4 xv = *(const float4*)&hs[k * 68 + r0];
            float4 wv = *(const float4*)&ws[k * EMB + c0];
            float xa[4] = {xv.x, xv.y, xv.z, xv.w};
            float wa[4] = {wv.x, wv.y, wv.z, wv.w};
#pragma unroll
            for (int i = 0; i < 4; ++i)
#pragma unroll
                for (int j = 0; j < 4; ++j)
                    a4[i][j] = fmaf(xa[i], wa[j], a4[i][j]);
        }
#pragma unroll
        for (int i = 0; i < 4; ++i) {
            long gr = row0 + r0 + i;
            if (gr < n)
                *(float4*)&u[gr * EMB + c0] = make_float4(a4[i][0], a4[i][1], a4[i][2], a4[i][3]);
        }
    }
}

// Fused layer-0 agg + layer-1 GEMM. 1024 threads = 16 waves, 64 nodes/block,
// 4 sequential nodes per wave. xt is [r][f] stride-65 (conflict-free).
template <bool BF_OUT>
__global__ __launch_bounds__(1024) void agg64_kernel(
    const unsigned short* __restrict__ tbl, const int* __restrict__ rowptr,
    const int* __restrict__ adj, const float* __restrict__ bias,
    const float* __restrict__ u, const float* __restrict__ W,
    void* __restrict__ outv, int n)
{
    __shared__ float xt[64 * ST];    // [r][f]
    __shared__ float ws[EMB * EMB];
    __shared__ float bs[EMB];

    int t = threadIdx.x;
    long node0 = (long)blockIdx.x * 64;
    int lane = t & 63;
    int wv = t >> 6;                 // wave id 0..15
    int p = lane & 15, g = lane >> 4;
    int f = 4 * p + g;               // this lane's feature

    {
        const float4* wg = (const float4*)W;
        float4* wl = (float4*)ws;
        wl[t] = wg[t];               // 1024 x 16B = full 64x64
    }
    if (t < EMB) bs[t] = bias[t];
    __syncthreads();

    const uint2* tb = (const uint2*)tbl;
    float bf = bs[f];
#pragma unroll
    for (int i = 0; i < 4; ++i) {
        int node = (int)node0 + wv * 4 + i;
        float val = 0.f;
        if (node < n) {
            int beg = rowptr[node];
            int end = rowptr[node + 1];
            float a0 = 0.f, a1 = 0.f, a2 = 0.f, a3 = 0.f;
            int e = beg + g;
            for (; e + 4 < end; e += 8) {
                int r0 = adj[e];
                int r1 = adj[e + 4];
                uint2 w0 = tb[(long)r0 * 16 + p];
                uint2 w1 = tb[(long)r1 * 16 + p];
                a0 += bflo(w0.x) + bflo(w1.x);
                a1 += bfhi(w0.x) + bfhi(w1.x);
                a2 += bflo(w0.y) + bflo(w1.y);
                a3 += bfhi(w0.y) + bfhi(w1.y);
            }
            if (e < end) {
                uint2 w0 = tb[(long)adj[e] * 16 + p];
                a0 += bflo(w0.x);
                a1 += bfhi(w0.x);
                a2 += bflo(w0.y);
                a3 += bfhi(w0.y);
            }
            a0 += __shfl_xor(a0, 16); a0 += __shfl_xor(a0, 32);
            a1 += __shfl_xor(a1, 16); a1 += __shfl_xor(a1, 32);
            a2 += __shfl_xor(a2, 16); a2 += __shfl_xor(a2, 32);
            a3 += __shfl_xor(a3, 16); a3 += __shfl_xor(a3, 32);
            int cnt = end - beg;
            float inv = 1.f / (float)(cnt > 0 ? cnt : 1);
            float av = (g == 0) ? a0 : ((g == 1) ? a1 : ((g == 2) ? a2 : a3));
            val = fmaxf(av * inv + bf + u[(long)node * EMB + f], 0.f);
        }
        xt[(wv * 4 + i) * ST + f] = val;
    }
    __syncthreads();

    // GEMM: out[r][c0..c0+3] = sum_k xt[r][k] * ws[k][c]; 1 row x 4 cols/thread
    int r = t >> 4;
    int c0 = (t & 15) * 4;
    float acc0 = 0.f, acc1 = 0.f, acc2 = 0.f, acc3 = 0.f;
#pragma unroll 8
    for (int k = 0; k < EMB; ++k) {
        float xa = xt[r * ST + k];
        float4 wv4 = *(const float4*)&ws[k * EMB + c0];
        acc0 = fmaf(xa, wv4.x, acc0);
        acc1 = fmaf(xa, wv4.y, acc1);
        acc2 = fmaf(xa, wv4.z, acc2);
        acc3 = fmaf(xa, wv4.w, acc3);
    }
    long gr = node0 + r;
    if (gr < n) {
        if (BF_OUT) {
            ushort4 o;
            o.x = f2bf(acc0); o.y = f2bf(acc1);
            o.z = f2bf(acc2); o.w = f2bf(acc3);
            *(ushort4*)((unsigned short*)outv + gr * EMB + c0) = o;
        } else {
            *(float4*)((float*)outv + gr * EMB + c0) = make_float4(acc0, acc1, acc2, acc3);
        }
    }
}

// Final layer: out[node] = relu(mean_nbr tb[nbr] + bias + out[node])  (RMW)
__global__ __launch_bounds__(256) void agg_bf16_kernel(
    const unsigned short* __restrict__ tbl, const int* __restrict__ rowptr,
    const int* __restrict__ adj, const float* __restrict__ bias,
    float* __restrict__ out, int n_dst)
{
    int lane = threadIdx.x & 63;
    int node = blockIdx.x * 4 + (threadIdx.x >> 6);
    if (node >= n_dst) return;
    int p = lane & 15;
    int g = lane >> 4;
    int beg = rowptr[node];
    int end = rowptr[node + 1];
    const uint2* tb = (const uint2*)tbl;
    float a0 = 0.f, a1 = 0.f, a2 = 0.f, a3 = 0.f;
    int e = beg + g;
    for (; e + 4 < end; e += 8) {
        int r0 = adj[e];
        int r1 = adj[e + 4];
        uint2 w0 = tb[(long)r0 * 16 + p];
        uint2 w1 = tb[(long)r1 * 16 + p];
        a0 += bflo(w0.x) + bflo(w1.x);
        a1 += bfhi(w0.x) + bfhi(w1.x);
        a2 += bflo(w0.y) + bflo(w1.y);
        a3 += bfhi(w0.y) + bfhi(w1.y);
    }
    if (e < end) {
        uint2 w0 = tb[(long)adj[e] * 16 + p];
        a0 += bflo(w0.x);
        a1 += bfhi(w0.x);
        a2 += bflo(w0.y);
        a3 += bfhi(w0.y);
    }
    a0 += __shfl_xor(a0, 16); a0 += __shfl_xor(a0, 32);
    a1 += __shfl_xor(a1, 16); a1 += __shfl_xor(a1, 32);
    a2 += __shfl_xor(a2, 16); a2 += __shfl_xor(a2, 32);
    a3 += __shfl_xor(a3, 16); a3 += __shfl_xor(a3, 32);
    if (g == 0) {
        int cnt = end - beg;
        float inv = 1.f / (float)(cnt > 0 ? cnt : 1);
        float4 bv = ((const float4*)bias)[p];
        float4* op = (float4*)(out + (long)node * EMB) + p;
        float4 ov = *op;
        float v0 = a0 * inv + bv.x + ov.x;
        float v1 = a1 * inv + bv.y + ov.y;
        float v2 = a2 * inv + bv.z + ov.z;
        float v3 = a3 * inv + bv.w + ov.w;
        *op = make_float4(fmaxf(v0, 0.f), fmaxf(v1, 0.f), fmaxf(v2, 0.f), fmaxf(v3, 0.f));
    }
}

extern "C" void kernel_launch(void* const* d_in, const int* in_sizes, int n_in,
                              void* d_out, int out_size, void* d_ws, size_t ws_size,
                              hipStream_t stream) {
    const float* cons_x     = (const float*)d_in[0];
    const float* var_x      = (const float*)d_in[1];
    const int*   eidx       = (const int*)d_in[3];
    const float* cons_shift = (const float*)d_in[4];
    const float* cons_scale = (const float*)d_in[5];
    const float* cons_w1    = (const float*)d_in[6];
    const float* cons_b1    = (const float*)d_in[7];
    const float* cons_w2    = (const float*)d_in[8];
    const float* cons_b2    = (const float*)d_in[9];
    const float* var_shift  = (const float*)d_in[10];
    const float* var_scale  = (const float*)d_in[11];
    const float* var_w1     = (const float*)d_in[12];
    const float* var_b1     = (const float*)d_in[13];
    const float* var_w2     = (const float*)d_in[14];
    const float* var_b2     = (const float*)d_in[15];
    const float* ll_w       = (const float*)d_in[18];
    const float* ll_b       = (const float*)d_in[19];
    const float* lr_w       = (const float*)d_in[20];

    const int nC = in_sizes[0] / 5;
    const int nV = in_sizes[1] / 19;
    const int E  = in_sizes[3] / 2;
    const int* src = eidx;       // constraint ids
    const int* dst = eidx + E;   // variable ids

    int shc = 0; while ((nC >> shc) >= 512) ++shc;
    int shv = 0; while ((nV >> shv) >= 512) ++shv;
    const int NBC = (nC + (1 << shc) - 1) >> shc;
    const int NBV = (nV + (1 << shv) - 1) >> shv;

    char* w = (char*)d_ws;
    auto alloc = [&](size_t bytes) {
        char* p = w;
        w += (bytes + 255) & ~(size_t)255;
        return p;
    };
    float* x_c = (float*)alloc((size_t)nC * EMB * 4);   // u_c buffer
    float* x_v = (float*)alloc((size_t)nV * EMB * 4);   // u_v buffer
    float* t_c = (float*)alloc((size_t)nC * EMB * 4);   // aliases: tmp_c, then bf16 table tb_c
    float* t_v = (float*)alloc((size_t)nV * EMB * 4);
    unsigned* tmp_c = (unsigned*)t_c;
    unsigned* tmp_v = (unsigned*)t_v;
    unsigned short* tb_c = (unsigned short*)t_c;
    unsigned short* tb_v = (unsigned short*)t_v;
    int* rp_v  = (int*)alloc((size_t)(nV + 1) * 4);
    int* rp_c  = (int*)alloc((size_t)(nC + 1) * 4);
    int* adj_v = (int*)alloc((size_t)E * 4);
    int* adj_c = (int*)alloc((size_t)E * 4);
    int* bkt   = (int*)alloc(4096 * 4);
    int* bb_c   = bkt;
    int* bb_v   = bkt + 1024;
    int* gcur_c = bkt + 2048;
    int* gcur_v = bkt + 3072;

    auto llw = [&](int l, int d) { return ll_w + (size_t)(l * 2 + d) * EMB * EMB; };
    auto lrw = [&](int l, int d) { return lr_w + (size_t)(l * 2 + d) * EMB * EMB; };
    auto llb = [&](int l, int d) { return ll_b + (size_t)(l * 2 + d) * EMB; };

    // ---- CSR build ----
    zero_int_kernel<<<16, 256, 0, stream>>>(bkt, 4096);
    bucket_hist_kernel<<<(E + CH - 1) / CH, 256, 0, stream>>>(src, dst, E, bb_c, bb_v, shc, shv, NBC, NBV);
    scan_buckets_kernel<<<1, 256, 0, stream>>>(bb_c, NBC, bb_v, NBV, E);
    bin_edges_kernel<<<(E + CH - 1) / CH, 256, 0, stream>>>(src, dst, E, bb_c, bb_v, gcur_c, gcur_v,
                                                            tmp_c, tmp_v, shc, shv, NBC, NBV);
    regroup2_kernel<<<NBV, 256, 0, stream>>>(tmp_v, bb_v, rp_v, adj_v, nV, shv, E, NBV);
    regroup2_kernel<<<NBC, 256, 0, stream>>>(tmp_c, bb_c, rp_c, adj_c, nC, shc, E, NBC);

    // ---- fused embed + layer-0 GEMMs (x never hits HBM) ----
    embed_fused_kernel<5><<<(nC + 63) / 64, 256, 0, stream>>>(
        cons_x, cons_shift, cons_scale, cons_w1, cons_b1, cons_w2, cons_b2,
        llw(0, 0), lrw(0, 1), tb_c, x_c, nC);
    embed_fused_kernel<19><<<(nV + 63) / 64, 256, 0, stream>>>(
        var_x, var_shift, var_scale, var_w1, var_b1, var_w2, var_b2,
        llw(0, 1), lrw(0, 0), tb_v, x_v, nV);

    // ---- layer-0 agg fused with layer-1 GEMM ----
    // var side: xhat_v @ lrw(1,0) -> d_out (u-term for final layer)
    agg64_kernel<false><<<(nV + 63) / 64, 1024, 0, stream>>>(
        tb_c, rp_v, adj_v, llb(0, 0), x_v, lrw(1, 0), d_out, nV);
    // cons side: xhat_c @ llw(1,0) -> tb_c (layer-1 table, overwrite)
    agg64_kernel<true><<<(nC + 63) / 64, 1024, 0, stream>>>(
        tb_v, rp_c, adj_c, llb(0, 1), x_c, llw(1, 0), tb_c, nC);

    // ---- final layer-1 var agg (RMW d_out) ----
    agg_bf16_kernel<<<(nV + 3) / 4, 256, 0, stream>>>(tb_c, rp_v, adj_v, llb(1, 0), (float*)d_out, nV);
}